// Round 14
// baseline (336.914 us; speedup 1.0000x reference)
//
#include <hip/hip_runtime.h>
#include <hip/hip_fp16.h>

constexpr int BLK = 256;

static inline int cdiv(long long a, int b) { return (int)((a + b - 1) / b); }

using v8h = __attribute__((ext_vector_type(8))) _Float16;
using v4f = __attribute__((ext_vector_type(4))) float;

// ---------------- utility ----------------

__global__ void zero_int(int* __restrict__ p, int n) {
    for (int i = blockIdx.x * blockDim.x + threadIdx.x; i < n; i += gridDim.x * blockDim.x)
        p[i] = 0;
}

// ---------------- degree / CSR build ----------------

__global__ void count_dst_off(const int* __restrict__ dst, int* __restrict__ cnt,
                              unsigned short* __restrict__ eoff, int E) {
    for (int i = blockIdx.x * blockDim.x + threadIdx.x; i < E; i += gridDim.x * blockDim.x)
        eoff[i] = (unsigned short)atomicAdd(&cnt[dst[i]], 1);
}

// block scans 1024 elements (256 threads x 4); also emits dis = rsqrt(cnt+1)
__global__ void scan1_dis(const int* __restrict__ cnt, int* __restrict__ rowptr,
                          int* __restrict__ bsum, float* __restrict__ dis, int N) {
    __shared__ int ts[256];
    int tid = threadIdx.x;
    int base = blockIdx.x * 1024 + tid * 4;
    int v[4], s = 0;
#pragma unroll
    for (int i = 0; i < 4; ++i) {
        v[i] = (base + i < N) ? cnt[base + i] : 0;
        s += v[i];
        if (base + i < N) dis[base + i] = rsqrtf((float)v[i] + 1.0f);
    }
    ts[tid] = s;
    __syncthreads();
    for (int off = 1; off < 256; off <<= 1) {
        int t = 0;
        if (tid >= off) t = ts[tid - off];
        __syncthreads();
        if (tid >= off) ts[tid] += t;
        __syncthreads();
    }
    int run = ts[tid] - s;
#pragma unroll
    for (int i = 0; i < 4; ++i) {
        if (base + i < N) rowptr[base + i] = run;
        run += v[i];
    }
    if (tid == 255) bsum[blockIdx.x] = ts[255];
}

// wave shuffle-scan over block sums (nb <= 64) + zero the BN sums buffer
__global__ void scan2z(const int* __restrict__ bsum, int* __restrict__ boff, int nb,
                       float* __restrict__ sums) {
    int tid = threadIdx.x;  // 640 threads
    if (tid < 64) {
        int orig = (tid < nb) ? bsum[tid] : 0;
        int v = orig;
#pragma unroll
        for (int off = 1; off < 64; off <<= 1) {
            int t = __shfl_up(v, off, 64);
            if (tid >= off) v += t;
        }
        if (tid < nb) boff[tid] = v - orig;  // exclusive
    } else if (tid < 64 + 576) {
        sums[tid - 64] = 0.0f;
    }
}

__global__ void scan3(int* __restrict__ rowptr, const int* __restrict__ boff, int N, int E) {
    int i = blockIdx.x * blockDim.x + threadIdx.x;
    if (i < N) rowptr[i] += boff[i >> 10];
    if (i == 0) rowptr[N] = E;
}

// atomic-free scatter of 2-B src index: slot = rowptr[dst] + eoff (bijection)
__global__ void csr_fill(const int* __restrict__ src, const int* __restrict__ dst,
                         const unsigned short* __restrict__ eoff,
                         const int* __restrict__ rowptr,
                         unsigned short* __restrict__ csrc, int E) {
    for (int i = blockIdx.x * blockDim.x + threadIdx.x; i < E; i += gridDim.x * blockDim.x) {
        csrc[rowptr[dst[i]] + (int)eoff[i]] = (unsigned short)src[i];
    }
}

// ---------------- MFMA GEMM: act(in)[N,K] @ W[K,96] (+bias) -> fp16 ----------
// HIN: fp16 input (else fp32). ACT: BN scale/shift computed in-block from
// (bnsums, gamma, beta) then ReLU, fused into A-fragments. STATS: epilogue
// accumulates column sum/sumsq into osums. Output is always fp16 (hout).

template <int K, bool ACT, bool BIAS, bool HIN, bool STATS>
__global__ __launch_bounds__(256) void gemm96m(const float* __restrict__ inf,
                                               const _Float16* __restrict__ inh,
                                               const float* __restrict__ W,
                                               const float* __restrict__ bias,
                                               const float* __restrict__ bnsums,
                                               const float* __restrict__ gamma,
                                               const float* __restrict__ beta,
                                               _Float16* __restrict__ hout,
                                               float* __restrict__ osums, int N) {
    constexpr int NK = K / 32;
    constexpr int LDK = K + 8;
    __shared__ __align__(16) _Float16 Wt[96 * LDK];
    __shared__ __align__(16) float ssl[ACT ? 192 : 1];
    __shared__ float sb[STATS ? 192 : 1];
    const int tid = threadIdx.x;
    for (int idx = tid; idx < K * 96; idx += 256) {
        int k = idx / 96, n = idx - k * 96;
        Wt[n * LDK + k] = (_Float16)W[idx];
    }
    if (ACT && tid < 96) {
        float inv_n = 1.0f / (float)N;
        float mean = bnsums[tid] * inv_n;
        float var = bnsums[96 + tid] * inv_n - mean * mean;
        float sc = gamma[tid] * rsqrtf(var + 1e-5f);
        ssl[tid] = sc;
        ssl[96 + tid] = beta[tid] - mean * sc;
    }
    if (STATS && tid < 192) sb[tid] = 0.0f;
    __syncthreads();

    const int wave = tid >> 6, lane = tid & 63;
    const int quad = lane >> 4, lm = lane & 15;
    const int rbase = blockIdx.x * 64 + wave * 16;
    int arow = rbase + lm;
    arow = arow < N ? arow : N - 1;

    v8h afr[NK];
#pragma unroll
    for (int kc = 0; kc < NK; ++kc) {
        v8h a;
        if (HIN) {
            a = *(const v8h*)&inh[(long long)arow * K + kc * 32 + quad * 8];
            if (ACT) {
#pragma unroll
                for (int j = 0; j < 8; ++j) {
                    int kk = kc * 32 + quad * 8 + j;
                    float f = fmaxf(fmaf((float)a[j], ssl[kk], ssl[96 + kk]), 0.0f);
                    a[j] = (_Float16)f;
                }
            }
        } else {
            const float* p = &inf[(long long)arow * K + kc * 32 + quad * 8];
            float4 p0 = *(const float4*)p;
            float4 p1 = *(const float4*)(p + 4);
            if (ACT) {
                int kk = kc * 32 + quad * 8;
                float4 sc0 = *(const float4*)&ssl[kk];
                float4 sc1 = *(const float4*)&ssl[kk + 4];
                float4 sh0 = *(const float4*)&ssl[96 + kk];
                float4 sh1 = *(const float4*)&ssl[96 + kk + 4];
                p0.x = fmaxf(fmaf(p0.x, sc0.x, sh0.x), 0.0f);
                p0.y = fmaxf(fmaf(p0.y, sc0.y, sh0.y), 0.0f);
                p0.z = fmaxf(fmaf(p0.z, sc0.z, sh0.z), 0.0f);
                p0.w = fmaxf(fmaf(p0.w, sc0.w, sh0.w), 0.0f);
                p1.x = fmaxf(fmaf(p1.x, sc1.x, sh1.x), 0.0f);
                p1.y = fmaxf(fmaf(p1.y, sc1.y, sh1.y), 0.0f);
                p1.z = fmaxf(fmaf(p1.z, sc1.z, sh1.z), 0.0f);
                p1.w = fmaxf(fmaf(p1.w, sc1.w, sh1.w), 0.0f);
            }
            a[0] = (_Float16)p0.x; a[1] = (_Float16)p0.y;
            a[2] = (_Float16)p0.z; a[3] = (_Float16)p0.w;
            a[4] = (_Float16)p1.x; a[5] = (_Float16)p1.y;
            a[6] = (_Float16)p1.z; a[7] = (_Float16)p1.w;
        }
        afr[kc] = a;
    }

    v4f acc[6];
#pragma unroll
    for (int t = 0; t < 6; ++t) {
        v4f c = {0.0f, 0.0f, 0.0f, 0.0f};
#pragma unroll
        for (int kc = 0; kc < NK; ++kc) {
            v8h b = *(const v8h*)&Wt[(t * 16 + lm) * LDK + kc * 32 + quad * 8];
            c = __builtin_amdgcn_mfma_f32_16x16x32_f16(afr[kc], b, c, 0, 0, 0);
        }
        acc[t] = c;
    }

    float ls[6], lq[6];
#pragma unroll
    for (int t = 0; t < 6; ++t) { ls[t] = 0.0f; lq[t] = 0.0f; }
#pragma unroll
    for (int t = 0; t < 6; ++t) {
        float bv = BIAS ? bias[t * 16 + lm] : 0.0f;
#pragma unroll
        for (int r = 0; r < 4; ++r) {
            int gr = rbase + quad * 4 + r;
            if (gr < N) {
                float o = acc[t][r] + bv;
                hout[(long long)gr * 96 + t * 16 + lm] = (_Float16)o;
                if (STATS) { ls[t] += o; lq[t] += o * o; }
            }
        }
    }
    if (STATS) {
#pragma unroll
        for (int t = 0; t < 6; ++t) {
            ls[t] += __shfl_xor(ls[t], 16);
            ls[t] += __shfl_xor(ls[t], 32);
            lq[t] += __shfl_xor(lq[t], 16);
            lq[t] += __shfl_xor(lq[t], 32);
        }
        if (quad == 0) {
#pragma unroll
            for (int t = 0; t < 6; ++t) {
                atomicAdd(&sb[t * 16 + lm], ls[t]);
                atomicAdd(&sb[96 + t * 16 + lm], lq[t]);
            }
        }
        __syncthreads();
        if (tid < 192) atomicAdd(&osums[tid], sb[tid]);
    }
}

// ---- MFMA final GEMM: l2norm(bn_relu(in_h) @ Wp2[96,64] + bp2) -> fp32 out --

__global__ __launch_bounds__(256) void gemm_finalm(const _Float16* __restrict__ in,
                                                   const float* __restrict__ W,
                                                   const float* __restrict__ bias,
                                                   const float* __restrict__ bnsums,
                                                   const float* __restrict__ gamma,
                                                   const float* __restrict__ beta,
                                                   float* __restrict__ out, int N) {
    constexpr int K = 96, NK = 3, LDK = K + 8;
    __shared__ __align__(16) _Float16 Wt[64 * LDK];
    __shared__ __align__(16) float ssl[192];
    const int tid = threadIdx.x;
    for (int idx = tid; idx < K * 64; idx += 256) {
        int k = idx / 64, n = idx - k * 64;
        Wt[n * LDK + k] = (_Float16)W[idx];
    }
    if (tid < 96) {
        float inv_n = 1.0f / (float)N;
        float mean = bnsums[tid] * inv_n;
        float var = bnsums[96 + tid] * inv_n - mean * mean;
        float sc = gamma[tid] * rsqrtf(var + 1e-5f);
        ssl[tid] = sc;
        ssl[96 + tid] = beta[tid] - mean * sc;
    }
    __syncthreads();

    const int wave = tid >> 6, lane = tid & 63;
    const int quad = lane >> 4, lm = lane & 15;
    const int rbase = blockIdx.x * 64 + wave * 16;
    int arow = rbase + lm;
    arow = arow < N ? arow : N - 1;

    v8h afr[NK];
#pragma unroll
    for (int kc = 0; kc < NK; ++kc) {
        v8h a = *(const v8h*)&in[(long long)arow * K + kc * 32 + quad * 8];
#pragma unroll
        for (int j = 0; j < 8; ++j) {
            int kk = kc * 32 + quad * 8 + j;
            float f = fmaxf(fmaf((float)a[j], ssl[kk], ssl[96 + kk]), 0.0f);
            a[j] = (_Float16)f;
        }
        afr[kc] = a;
    }

    v4f acc[4];
#pragma unroll
    for (int t = 0; t < 4; ++t) {
        v4f c = {0.0f, 0.0f, 0.0f, 0.0f};
#pragma unroll
        for (int kc = 0; kc < NK; ++kc) {
            v8h b = *(const v8h*)&Wt[(t * 16 + lm) * LDK + kc * 32 + quad * 8];
            c = __builtin_amdgcn_mfma_f32_16x16x32_f16(afr[kc], b, c, 0, 0, 0);
        }
        float bv = bias[t * 16 + lm];
        c[0] += bv; c[1] += bv; c[2] += bv; c[3] += bv;
        acc[t] = c;
    }

    float sq[4];
#pragma unroll
    for (int r = 0; r < 4; ++r) {
        float s = acc[0][r] * acc[0][r] + acc[1][r] * acc[1][r] +
                  acc[2][r] * acc[2][r] + acc[3][r] * acc[3][r];
#pragma unroll
        for (int m = 1; m < 16; m <<= 1) s += __shfl_xor(s, m, 64);
        sq[r] = 1.0f / fmaxf(sqrtf(s), 1e-12f);
    }
#pragma unroll
    for (int r = 0; r < 4; ++r) {
        int gr = rbase + quad * 4 + r;
        if (gr < N) {
#pragma unroll
            for (int t = 0; t < 4; ++t)
                out[(long long)gr * 64 + t * 16 + lm] = acc[t][r] * sq[r];
        }
    }
}

// ---------------- CSR pull aggregation (fp16 in AND out, 2-B edge index) -----
// out_h[n] = fp16( bias + dis[n]^2 * h(xw[n]) + sum_e dis[s]*dis[n]*h(xw[s]) )
// 12 threads per node, 8 cols (16 B) each, edge loop unrolled x8/x4 (R9 form).

__device__ __forceinline__ void acc_edge(float* acc, const __half2* h, float w) {
#pragma unroll
    for (int k = 0; k < 4; ++k) {
        float2 f = __half22float2(h[k]);
        acc[2 * k + 0] = fmaf(f.x, w, acc[2 * k + 0]);
        acc[2 * k + 1] = fmaf(f.y, w, acc[2 * k + 1]);
    }
}

__global__ __launch_bounds__(256) void agg96h(const __half* __restrict__ hxw,
                                              const int* __restrict__ rowptr,
                                              const unsigned short* __restrict__ csrc,
                                              const float* __restrict__ dis,
                                              const float* __restrict__ bias,
                                              _Float16* __restrict__ hout, int N) {
    int idx = blockIdx.x * 256 + threadIdx.x;
    if (idx >= N * 12) return;
    int n = idx / 12, c8 = idx % 12;
    int ch = c8 * 8;
    float dn = dis[n];
    float acc[8];
    {
        float dd = dn * dn;
        float4 g = *(const float4*)&hxw[(long long)n * 96 + ch];
        const __half2* hs = (const __half2*)&g;
#pragma unroll
        for (int k = 0; k < 4; ++k) {
            float2 f = __half22float2(hs[k]);
            acc[2 * k + 0] = fmaf(f.x, dd, bias[ch + 2 * k + 0]);
            acc[2 * k + 1] = fmaf(f.y, dd, bias[ch + 2 * k + 1]);
        }
    }
    int e = rowptr[n], e1 = rowptr[n + 1];
    for (; e + 7 < e1; e += 8) {
        int s[8];
        float w[8];
        float4 g[8];
#pragma unroll
        for (int j = 0; j < 8; ++j) s[j] = csrc[e + j];
#pragma unroll
        for (int j = 0; j < 8; ++j) w[j] = dis[s[j]] * dn;
#pragma unroll
        for (int j = 0; j < 8; ++j)
            g[j] = *(const float4*)&hxw[(long long)s[j] * 96 + ch];
#pragma unroll
        for (int j = 0; j < 8; ++j) acc_edge(acc, (const __half2*)&g[j], w[j]);
    }
    for (; e + 3 < e1; e += 4) {
        int s[4];
        float w[4];
        float4 g[4];
#pragma unroll
        for (int j = 0; j < 4; ++j) s[j] = csrc[e + j];
#pragma unroll
        for (int j = 0; j < 4; ++j) w[j] = dis[s[j]] * dn;
#pragma unroll
        for (int j = 0; j < 4; ++j)
            g[j] = *(const float4*)&hxw[(long long)s[j] * 96 + ch];
#pragma unroll
        for (int j = 0; j < 4; ++j) acc_edge(acc, (const __half2*)&g[j], w[j]);
    }
    for (; e < e1; ++e) {
        int s0 = csrc[e];
        float w0 = dis[s0] * dn;
        float4 g0 = *(const float4*)&hxw[(long long)s0 * 96 + ch];
        acc_edge(acc, (const __half2*)&g0, w0);
    }
    v8h o;
#pragma unroll
    for (int j = 0; j < 8; ++j) o[j] = (_Float16)acc[j];
    *(v8h*)&hout[(long long)n * 96 + ch] = o;
}

// ---------------- BN stats over fp16 buffer (coalesced grid-stride) ----------

__global__ __launch_bounds__(256) void bn_stats96h(const _Float16* __restrict__ h,
                                                   float* __restrict__ sums, int N) {
    __shared__ float sb[192];
    const int tid = threadIdx.x;
    if (tid < 192) sb[tid] = 0.0f;
    __syncthreads();
    int g = blockIdx.x * 256 + tid;
    int total = N * 12, stride = gridDim.x * 256;
    int c8 = g % 12;  // per-row label permutation covers all groups (see R13 note)
    float s8[8], q8[8];
#pragma unroll
    for (int j = 0; j < 8; ++j) { s8[j] = 0.0f; q8[j] = 0.0f; }
    for (int i = g; i < total; i += stride) {
        int n = i / 12;
        v8h v = *(const v8h*)&h[(long long)n * 96 + c8 * 8];
#pragma unroll
        for (int j = 0; j < 8; ++j) {
            float f = (float)v[j];
            s8[j] += f;
            q8[j] += f * f;
        }
    }
#pragma unroll
    for (int j = 0; j < 8; ++j) {
        atomicAdd(&sb[c8 * 8 + j], s8[j]);
        atomicAdd(&sb[96 + c8 * 8 + j], q8[j]);
    }
    __syncthreads();
    if (tid < 192) atomicAdd(&sums[tid], sb[tid]);
}

// ---------------- launch ----------------

extern "C" void kernel_launch(void* const* d_in, const int* in_sizes, int n_in,
                              void* d_out, int out_size, void* d_ws, size_t ws_size,
                              hipStream_t stream) {
    const float* x   = (const float*)d_in[0];
    const int*   ei  = (const int*)d_in[1];
    const float* W1  = (const float*)d_in[2];
    const float* b1  = (const float*)d_in[3];
    const float* g1  = (const float*)d_in[4];
    const float* be1 = (const float*)d_in[5];
    const float* W2  = (const float*)d_in[6];
    const float* b2  = (const float*)d_in[7];
    const float* g2  = (const float*)d_in[8];
    const float* be2 = (const float*)d_in[9];
    const float* Wp1 = (const float*)d_in[10];
    const float* bp1 = (const float*)d_in[11];
    const float* gp  = (const float*)d_in[12];
    const float* bep = (const float*)d_in[13];
    const float* Wp2 = (const float*)d_in[14];
    const float* bp2 = (const float*)d_in[15];

    const int N = in_sizes[0] / 128;   // 50000 (< 2^16 -> uint16 indices ok)
    const int E = in_sizes[1] / 2;     // 800000
    const int* src = ei;
    const int* dst = ei + E;

    // workspace layout (~24 MB)
    char* w = (char*)d_ws;
    auto alloc = [&](size_t bytes) { char* p = w; w += (bytes + 15) & ~size_t(15); return p; };
    int*            cnt    = (int*)alloc((size_t)N * 4);
    int*            rowptr = (int*)alloc((size_t)(N + 1) * 4);
    int*            bsum   = (int*)alloc(64 * 4);
    int*            boff   = (int*)alloc(64 * 4);
    float*          dis    = (float*)alloc((size_t)N * 4);
    unsigned short* eoff   = (unsigned short*)alloc((size_t)E * 2);
    unsigned short* csrc   = (unsigned short*)alloc((size_t)E * 2);
    _Float16*       hA     = (_Float16*)alloc((size_t)N * 96 * 2);  // GEMM outputs
    _Float16*       hB     = (_Float16*)alloc((size_t)N * 96 * 2);  // agg outputs
    float*          sums   = (float*)alloc(576 * 4);
    float* sums1 = sums, *sums2 = sums + 192, *sums3 = sums + 384;

    float* out = (float*)d_out;

    const int gE  = cdiv(E, BLK);                  // 3125 blocks
    const int gG  = cdiv(N, 64);                   // 782 gemm blocks
    const int gA  = cdiv((long long)N * 12, BLK);  // 2344 agg blocks
    const int nb  = cdiv(N, 1024);                 // scan blocks (49)

    // CSR build (atomic-free 2-B scatter: slot = rowptr[dst] + eoff)
    zero_int<<<cdiv(N, BLK), BLK, 0, stream>>>(cnt, N);
    count_dst_off<<<gE, BLK, 0, stream>>>(dst, cnt, eoff, E);
    scan1_dis<<<nb, 256, 0, stream>>>(cnt, rowptr, bsum, dis, N);
    scan2z<<<1, 640, 0, stream>>>(bsum, boff, nb, sums);
    scan3<<<cdiv(N, BLK), BLK, 0, stream>>>(rowptr, boff, N, E);
    csr_fill<<<gE, BLK, 0, stream>>>(src, dst, eoff, rowptr, csrc, E);

    // layer 1: GEMM (fp32 x in, fp16 out) -> agg (fp16->fp16) -> stats(fp16)
    gemm96m<128, false, false, false, false><<<gG, 256, 0, stream>>>(
        x, nullptr, W1, nullptr, nullptr, nullptr, nullptr, hA, nullptr, N);
    agg96h<<<gA, 256, 0, stream>>>((const __half*)hA, rowptr, csrc, dis, b1, hB, N);
    bn_stats96h<<<512, 256, 0, stream>>>(hB, sums1, N);

    // layer 2: GEMM (fp16 in + BN1 fused, fp16 out) -> agg -> stats
    gemm96m<96, true, false, true, false><<<gG, 256, 0, stream>>>(
        nullptr, hB, W2, nullptr, sums1, g1, be1, hA, nullptr, N);
    agg96h<<<gA, 256, 0, stream>>>((const __half*)hA, rowptr, csrc, dis, b2, hB, N);
    bn_stats96h<<<512, 256, 0, stream>>>(hB, sums2, N);

    // projector linear 1: fp16 in + BN2 fused, bias, fp16 out, BN3 stats fused
    gemm96m<96, true, true, true, true><<<gG, 256, 0, stream>>>(
        nullptr, hB, Wp1, bp1, sums2, g2, be2, hA, sums3, N);

    // projector linear 2: fp16 in + BN3 fused + bias + L2 normalize -> fp32 out
    gemm_finalm<<<gG, 256, 0, stream>>>(hA, Wp2, bp2, sums3, gp, bep, out, N);
}